// Round 18
// baseline (22.751 us; speedup 1.0000x reference)
//
#include <hip/hip_runtime.h>
#include <math.h>

#define NUM_CLASSES 80
#define OBJ_BLOCKS 1536                 // 3 scales x 16 batch x 32 targets
#define NEG0_BLOCKS 300                 // 76800 float4 / 256 (exact)
#define NEG1_BLOCKS 75                  // 19200 / 256 (exact)
#define NEG2_BLOCKS 19                  // ceil(4800 / 256)
#define NEG_BLOCKS (NEG0_BLOCKS + NEG1_BLOCKS + NEG2_BLOCKS)   // 394
#define TOTAL_BLOCKS (OBJ_BLOCKS + NEG_BLOCKS)
#define NEG_BASE (OBJ_BLOCKS * 8)       // float offset of neg partials in ws

// ---- math helpers (match jax.nn.log_sigmoid / sigmoid in f32) ----
__device__ __forceinline__ float softplusf_(float x) {
    return x > 0.f ? x + log1pf(expf(-x)) : log1pf(expf(x));
}
__device__ __forceinline__ float sigmoidf_(float x) {
    return 1.f / (1.f + expf(-x));
}
// focal_bce(x, t=0) = softplus(x) * sigmoid(x)^2
__device__ __forceinline__ float focal0(float x) {
    float s = sigmoidf_(x);
    return softplusf_(x) * s * s;
}
// focal_bce(x, t=1) = softplus(-x) * sigmoid(-x)^2
__device__ __forceinline__ float focal1(float x) {
    float s = sigmoidf_(-x);
    return softplusf_(-x) * s * s;
}

// ws layout (floats) — R8/R16/R17-proven: every slot written unconditionally
// by plain distinct-address stores; kernel boundary = completion barrier.
//   [bid*8 .. +7]   obj slot: [0]=xy [1]=wh [2]=cls [3]=pos [4]=neg_corr
//                   [5]=count [6,7]=0          (bid < 1536)
//   [NEG_BASE + q]  neg partial of neg-block q  (q < 394)

template<int NI, int PLANE4>
__device__ __forceinline__ float neg_sum2(const float* __restrict__ P,
                                          int lq, int f) {
    float sum = 0.f;
    #pragma unroll
    for (int k = 0; k < 2; ++k) {
        const int idx = lq * 256 + k * 128 + f;
        if (idx < NI) {
            const int plane = idx / PLANE4;          // compile-time divisor
            const int r4 = idx - plane * PLANE4;
            const int b = plane / 3;
            const int a = plane - b * 3;
            const float4 v = *reinterpret_cast<const float4*>(
                P + (size_t)(b * 255 + a * 85 + 4) * (PLANE4 * 4)
                  + (size_t)r4 * 4);
            sum += focal0(v.x) + focal0(v.y) + focal0(v.z) + focal0(v.w);
        }
    }
    return sum;
}

__global__ __launch_bounds__(128)
void work_kernel(const float* __restrict__ p0,
                 const float* __restrict__ p1,
                 const float* __restrict__ p2,
                 const float* __restrict__ tgt,
                 float* __restrict__ ws) {
    __shared__ int      s_cell[32];
    __shared__ int      s_off[32];      // channel-0 offset within batch slab
    __shared__ int      s_cls[32];
    __shared__ float    s_geo[32][4];   // tx, ty, tw_t, th_t
    __shared__ unsigned s_um[3];        // class-union (block-uniform result)
    __shared__ int      s_winflag;
    __shared__ float    s_d[6];         // lane 0..4 direct scalars (+corr)
    __shared__ float    s_cls_red[2];   // per-wave cls partial
    __shared__ float    s_ns[2];

    const int bid = blockIdx.x;
    const int f   = threadIdx.x;          // 128 threads = 2 waves
    const int lane = f & 63;
    const int wid  = f >> 6;

    if (bid < OBJ_BLOCKS) {
        // ====== object path: one block per (scale, batch, target) ======
        // R18: only cls (f=5..84) needs a cross-lane reduce; lanes 0..4
        // write their scalar categories directly to LDS (R17's 5-acc
        // 30-shfl reduce was 96% wasted issue).
        const int s = bid >> 9;            // /512
        const int r = bid & 511;
        const int b = r >> 5;              // /32
        const int t = r & 31;
        const int H  = (s == 0) ? 80 : (s == 1 ? 40 : 20);
        const int W  = H;
        const int HW = H * W;

        float aw0, aw1, aw2, ah0, ah1, ah2;
        if (s == 0) { aw0=10.f/640.f; aw1=16.f/640.f; aw2=33.f/640.f;
                      ah0=13.f/640.f; ah1=30.f/640.f; ah2=23.f/640.f; }
        else if (s == 1) { aw0=30.f/640.f; aw1=62.f/640.f; aw2=59.f/640.f;
                           ah0=61.f/640.f; ah1=45.f/640.f; ah2=119.f/640.f; }
        else { aw0=116.f/640.f; aw1=156.f/640.f; aw2=373.f/640.f;
               ah0=90.f/640.f;  ah1=198.f/640.f; ah2=326.f/640.f; }

        // Phase 1: per-target cell + geometry + class (threads 0..31)
        if (f < 32) {
            const float* tg = tgt + (size_t)(b * 32 + f) * 5;
            const float w = tg[3], h = tg[4];
            int cell = -1, off = 0;
            float g0 = 0.f, g1 = 0.f, g2 = 0.f, g3 = 0.f;
            if (w > 0.f && h > 0.f) {
                // argmax IoU over 3 anchors, first-max on ties (strict >)
                float best = -1.f; int ba = 0;
                float inter = fminf(w, aw0) * fminf(h, ah0);
                float iou = inter / (w * h + aw0 * ah0 - inter + 1e-6f);
                if (iou > best) { best = iou; ba = 0; }
                inter = fminf(w, aw1) * fminf(h, ah1);
                iou = inter / (w * h + aw1 * ah1 - inter + 1e-6f);
                if (iou > best) { best = iou; ba = 1; }
                inter = fminf(w, aw2) * fminf(h, ah2);
                iou = inter / (w * h + aw2 * ah2 - inter + 1e-6f);
                if (iou > best) { best = iou; ba = 2; }
                const float aw = (ba == 0) ? aw0 : (ba == 1 ? aw1 : aw2);
                const float ah = (ba == 0) ? ah0 : (ba == 1 ? ah1 : ah2);
                const float xw = tg[1] * (float)W, yh = tg[2] * (float)H;
                int gi = (int)xw; gi = min(max(gi, 0), W - 1); // trunc==astype(i32)
                int gj = (int)yh; gj = min(max(gj, 0), H - 1);
                cell = (ba * H + gj) * W + gi;                 // b uniform in block
                off  = ba * 85 * HW + gj * W + gi;
                g0 = xw - (float)gi;
                g1 = yh - (float)gj;
                g2 = logf(w / aw + 1e-6f);
                g3 = logf(h / ah + 1e-6f);
            }
            s_cell[f] = cell;
            s_off[f]  = off;
            s_cls[f]  = (int)tg[0];
            s_geo[f][0] = g0; s_geo[f][1] = g1;
            s_geo[f][2] = g2; s_geo[f][3] = g3;
        }
        __syncthreads();

        const int mycell = s_cell[t];

        // Issue the gather EARLY: winner/union VALU hides under its latency.
        float val = 0.f;
        if (f < 85 && mycell >= 0) {
            const float* P = (s == 0) ? p0 : (s == 1 ? p1 : p2);
            val = P[(size_t)b * 255 * HW + (size_t)s_off[t] + (size_t)f * HW];
        }

        // Lane-parallel winner + class-union on wave 0 (R17-proven).
        if (f < 64) {
            bool same = false; int kc = 0;
            if (lane < 32) {
                same = (mycell >= 0) && (s_cell[lane] == mycell);
                kc   = s_cls[lane];
            }
            const unsigned long long dupm = __ballot(same && (lane > t));
            const unsigned bit = 1u << (kc & 31);
            unsigned m0 = (same && (kc >> 5) == 0) ? bit : 0u;
            unsigned m1 = (same && (kc >> 5) == 1) ? bit : 0u;
            unsigned m2 = (same && (kc >> 5) == 2) ? bit : 0u;
            #pragma unroll
            for (int o = 1; o < 64; o <<= 1) {
                m0 |= __shfl_xor(m0, o, 64);
                m1 |= __shfl_xor(m1, o, 64);
                m2 |= __shfl_xor(m2, o, 64);
            }
            if (lane == 0) {
                s_um[0] = m0; s_um[1] = m1; s_um[2] = m2;
                s_winflag = (mycell >= 0 && dupm == 0ull) ? 1 : 0;
            }
        }
        __syncthreads();

        const bool winner = (s_winflag != 0);        // block-uniform

        // cls accumulator (f=5..84); lanes 0..4 write scalars directly.
        float acls = 0.f;
        if (winner && f < 85) {
            if (f == 0) {
                const float d = sigmoidf_(val) - s_geo[t][0];
                s_d[0] = d * d;
            } else if (f == 1) {
                const float d = sigmoidf_(val) - s_geo[t][1];
                s_d[1] = d * d;
            } else if (f == 2) {
                const float e = val - s_geo[t][2];
                s_d[2] = e * e;
            } else if (f == 3) {
                const float e = val - s_geo[t][3];
                s_d[3] = e * e;
            } else if (f == 4) {
                s_d[4] = focal1(val);
                s_d[5] = -focal0(val);   // correction to all-cell neg sum
            } else {
                const int c = f - 5;
                const bool ts = (c < 32) ? ((s_um[0] >> c) & 1)
                              : (c < 64) ? ((s_um[1] >> (c - 32)) & 1)
                                         : ((s_um[2] >> (c - 64)) & 1);
                acls = ts ? focal1(val) : focal0(val);
            }
        }
        // single-accumulator wave reduce (6 shfls instead of R17's 30)
        #pragma unroll
        for (int o = 32; o; o >>= 1) acls += __shfl_down(acls, o, 64);
        if (lane == 0) s_cls_red[wid] = acls;
        __syncthreads();

        float* slot = ws + (size_t)bid * 8;          // plain distinct-address
        if (f < 8) {                                 // stores (R8-proven)
            float v = 0.f;
            if (winner) {
                if (f == 0)      v = s_d[0] + s_d[1];
                else if (f == 1) v = s_d[2] + s_d[3];
                else if (f == 2) v = s_cls_red[0] + s_cls_red[1];
                else if (f == 3) v = s_d[4];
                else if (f == 4) v = s_d[5];
                else if (f == 5) v = 1.f;
            }
            slot[f] = v;
        }
    } else {
        // ============== all-cell negative path: 2 float4 / thread ==========
        const int q = bid - OBJ_BLOCKS;              // 0..393
        float sum;
        if (q < NEG0_BLOCKS)
            sum = neg_sum2<76800, 1600>(p0, q, f);
        else if (q < NEG0_BLOCKS + NEG1_BLOCKS)
            sum = neg_sum2<19200, 400>(p1, q - NEG0_BLOCKS, f);
        else
            sum = neg_sum2<4800, 100>(p2, q - NEG0_BLOCKS - NEG1_BLOCKS, f);
        #pragma unroll
        for (int off = 32; off; off >>= 1) sum += __shfl_down(sum, off, 64);
        if ((f & 63) == 0) s_ns[f >> 6] = sum;
        __syncthreads();
        if (f == 0) ws[NEG_BASE + q] = s_ns[0] + s_ns[1];
    }
}

// ---- Kernel F: reduce all partials + finalize scalar ----
__global__ __launch_bounds__(512)
void finalize_kernel(const float* __restrict__ ws,
                     float* __restrict__ out) {
    __shared__ float s_red[8][6];
    __shared__ float s_nred[8][3];
    __shared__ float s_total;
    const int tid  = threadIdx.x;            // 512 threads
    const int lane = tid & 63;
    const int wid  = tid >> 6;
    if (tid == 0) s_total = 0.f;

    // neg partials -> per-scale sums (one per thread, q < 394)
    float n0 = 0.f, n1 = 0.f, n2 = 0.f;
    if (tid < NEG_BLOCKS) {
        const float v = ws[NEG_BASE + tid];
        if (tid < NEG0_BLOCKS)                    n0 = v;
        else if (tid < NEG0_BLOCKS + NEG1_BLOCKS) n1 = v;
        else                                      n2 = v;
    }
    #pragma unroll
    for (int off = 32; off; off >>= 1) {
        n0 += __shfl_down(n0, off, 64);
        n1 += __shfl_down(n1, off, 64);
        n2 += __shfl_down(n2, off, 64);
    }
    if (lane == 0) { s_nred[wid][0] = n0; s_nred[wid][1] = n1; s_nred[wid][2] = n2; }

    // obj slots -> per-scale sums + final scalar
    #pragma unroll 1
    for (int s = 0; s < 3; ++s) {
        const float* slot = ws + (size_t)(s * 512 + tid) * 8;
        float v[6];
        #pragma unroll
        for (int k = 0; k < 6; ++k) v[k] = slot[k];
        #pragma unroll
        for (int off = 32; off; off >>= 1)
            #pragma unroll
            for (int k = 0; k < 6; ++k) v[k] += __shfl_down(v[k], off, 64);
        if (lane == 0) {
            #pragma unroll
            for (int k = 0; k < 6; ++k) s_red[wid][k] = v[k];
        }
        __syncthreads();
        if (tid == 0) {
            float sum[6] = {0.f, 0.f, 0.f, 0.f, 0.f, 0.f};
            float negs = 0.f;
            for (int wv = 0; wv < 8; ++wv) {
                #pragma unroll
                for (int k = 0; k < 6; ++k) sum[k] += s_red[wv][k];
                negs += s_nred[wv][s];
            }
            const float Ns = (s == 0) ? (float)(16 * 3 * 6400)
                           : (s == 1) ? (float)(16 * 3 * 1600)
                                      : (float)(16 * 3 * 400);
            const float n_obj   = sum[5];
            const float n_noobj = Ns - n_obj;
            const float lxywh = (sum[0] + sum[1]) / fmaxf(2.f * n_obj, 1.f);
            const float lcls  = sum[2] / fmaxf(n_obj * (float)NUM_CLASSES, 1.f);
            const float lpos  = sum[3] / fmaxf(n_obj, 1.f);
            const float lneg  = (negs + sum[4]) / fmaxf(n_noobj, 1.f);
            const float has   = (n_obj > 0.f) ? 1.f : 0.f;
            s_total += 5.f * lxywh * has + lpos * has + 0.5f * lneg + lcls * has;
        }
        __syncthreads();
    }
    if (tid == 0) out[0] = s_total / 3.f;
}

extern "C" void kernel_launch(void* const* d_in, const int* in_sizes, int n_in,
                              void* d_out, int out_size, void* d_ws, size_t ws_size,
                              hipStream_t stream) {
    const float* p0  = (const float*)d_in[0];
    const float* p1  = (const float*)d_in[1];
    const float* p2  = (const float*)d_in[2];
    const float* tgt = (const float*)d_in[3];
    float* ws  = (float*)d_ws;   // needs (1536*8 + 394) floats ~= 51 KB
    float* out = (float*)d_out;

    work_kernel<<<TOTAL_BLOCKS, 128, 0, stream>>>(p0, p1, p2, tgt, ws);
    finalize_kernel<<<1, 512, 0, stream>>>(ws, out);
}

// Round 19
// 20.797 us; speedup vs baseline: 1.0939x; 1.0939x over previous
//
#include <hip/hip_runtime.h>
#include <math.h>

#define NUM_CLASSES 80
#define OBJ_BLOCKS 1536                 // 3 scales x 16 batch x 32 targets
#define NEG_BLOCKS 788                  // ceil(100800 float4 / 128)
#define TOTAL_BLOCKS (OBJ_BLOCKS + NEG_BLOCKS)
#define NEG_BASE (OBJ_BLOCKS * 8)       // float offset of neg partials in ws

// ---- math helpers (match jax.nn.log_sigmoid / sigmoid in f32) ----
__device__ __forceinline__ float softplusf_(float x) {
    return x > 0.f ? x + log1pf(expf(-x)) : log1pf(expf(x));
}
__device__ __forceinline__ float sigmoidf_(float x) {
    return 1.f / (1.f + expf(-x));
}
// focal_bce(x, t=0) = softplus(x) * sigmoid(x)^2
__device__ __forceinline__ float focal0(float x) {
    float s = sigmoidf_(x);
    return softplusf_(x) * s * s;
}
// focal_bce(x, t=1) = softplus(-x) * sigmoid(-x)^2
__device__ __forceinline__ float focal1(float x) {
    float s = sigmoidf_(-x);
    return softplusf_(-x) * s * s;
}

// ws layout (floats) — R8/R16-proven: every slot written unconditionally by
// plain distinct-address stores; kernel boundary = completion barrier.
//   [bid*8 .. +7]   obj slot: [0]=xy [1]=wh [2]=cls [3]=pos [4]=neg_corr
//                   [5]=count [6,7]=0          (bid < 1536)
//   [NEG_BASE + q]  neg partial of neg-block q  (q < 788)

__global__ __launch_bounds__(128)
void work_kernel(const float* __restrict__ p0,
                 const float* __restrict__ p1,
                 const float* __restrict__ p2,
                 const float* __restrict__ tgt,
                 float* __restrict__ ws) {
    __shared__ int      s_cell[32];
    __shared__ int      s_off[32];      // channel-0 offset within batch slab
    __shared__ int      s_cls[32];
    __shared__ float    s_geo[32][4];   // tx, ty, tw_t, th_t
    __shared__ unsigned s_um[3];        // class-union (block-uniform result)
    __shared__ int      s_winflag;
    __shared__ float    s_red[2][5];    // per-wave category partials
    __shared__ float    s_ns[2];

    const int bid = blockIdx.x;
    const int f   = threadIdx.x;          // 128 threads = 2 waves
    const int lane = f & 63;
    const int wid  = f >> 6;

    if (bid < OBJ_BLOCKS) {
        // ====== object path: one block per (scale, batch, target) ======
        // R17 optimum: winner/union is BLOCK-UNIFORM -> lane-parallel on
        // wave 0 (1 ballot + 6-step shfl-OR) instead of 32-iter LDS loops
        // on all 128 threads; category sums via 5-acc shfl reduce.
        const int s = bid >> 9;            // /512
        const int r = bid & 511;
        const int b = r >> 5;              // /32
        const int t = r & 31;
        const int H  = (s == 0) ? 80 : (s == 1 ? 40 : 20);
        const int W  = H;
        const int HW = H * W;

        float aw0, aw1, aw2, ah0, ah1, ah2;
        if (s == 0) { aw0=10.f/640.f; aw1=16.f/640.f; aw2=33.f/640.f;
                      ah0=13.f/640.f; ah1=30.f/640.f; ah2=23.f/640.f; }
        else if (s == 1) { aw0=30.f/640.f; aw1=62.f/640.f; aw2=59.f/640.f;
                           ah0=61.f/640.f; ah1=45.f/640.f; ah2=119.f/640.f; }
        else { aw0=116.f/640.f; aw1=156.f/640.f; aw2=373.f/640.f;
               ah0=90.f/640.f;  ah1=198.f/640.f; ah2=326.f/640.f; }

        // Phase 1: per-target cell + geometry + class (threads 0..31)
        if (f < 32) {
            const float* tg = tgt + (size_t)(b * 32 + f) * 5;
            const float w = tg[3], h = tg[4];
            int cell = -1, off = 0;
            float g0 = 0.f, g1 = 0.f, g2 = 0.f, g3 = 0.f;
            if (w > 0.f && h > 0.f) {
                // argmax IoU over 3 anchors, first-max on ties (strict >)
                float best = -1.f; int ba = 0;
                float inter = fminf(w, aw0) * fminf(h, ah0);
                float iou = inter / (w * h + aw0 * ah0 - inter + 1e-6f);
                if (iou > best) { best = iou; ba = 0; }
                inter = fminf(w, aw1) * fminf(h, ah1);
                iou = inter / (w * h + aw1 * ah1 - inter + 1e-6f);
                if (iou > best) { best = iou; ba = 1; }
                inter = fminf(w, aw2) * fminf(h, ah2);
                iou = inter / (w * h + aw2 * ah2 - inter + 1e-6f);
                if (iou > best) { best = iou; ba = 2; }
                const float aw = (ba == 0) ? aw0 : (ba == 1 ? aw1 : aw2);
                const float ah = (ba == 0) ? ah0 : (ba == 1 ? ah1 : ah2);
                const float xw = tg[1] * (float)W, yh = tg[2] * (float)H;
                int gi = (int)xw; gi = min(max(gi, 0), W - 1); // trunc==astype(i32)
                int gj = (int)yh; gj = min(max(gj, 0), H - 1);
                cell = (ba * H + gj) * W + gi;                 // b uniform in block
                off  = ba * 85 * HW + gj * W + gi;
                g0 = xw - (float)gi;
                g1 = yh - (float)gj;
                g2 = logf(w / aw + 1e-6f);
                g3 = logf(h / ah + 1e-6f);
            }
            s_cell[f] = cell;
            s_off[f]  = off;
            s_cls[f]  = (int)tg[0];
            s_geo[f][0] = g0; s_geo[f][1] = g1;
            s_geo[f][2] = g2; s_geo[f][3] = g3;
        }
        __syncthreads();

        const int mycell = s_cell[t];

        // Issue the gather EARLY: winner/union VALU hides under its latency.
        float val = 0.f;
        if (f < 85 && mycell >= 0) {
            const float* P = (s == 0) ? p0 : (s == 1 ? p1 : p2);
            val = P[(size_t)b * 255 * HW + (size_t)s_off[t] + (size_t)f * HW];
        }

        // Lane-parallel winner + class-union on wave 0: lane l tests
        // target l only; dup via ballot; union via 6-step shfl-OR.
        if (f < 64) {
            bool same = false; int kc = 0;
            if (lane < 32) {
                same = (mycell >= 0) && (s_cell[lane] == mycell);
                kc   = s_cls[lane];
            }
            const unsigned long long dupm = __ballot(same && (lane > t));
            const unsigned bit = 1u << (kc & 31);
            unsigned m0 = (same && (kc >> 5) == 0) ? bit : 0u;
            unsigned m1 = (same && (kc >> 5) == 1) ? bit : 0u;
            unsigned m2 = (same && (kc >> 5) == 2) ? bit : 0u;
            #pragma unroll
            for (int o = 1; o < 64; o <<= 1) {
                m0 |= __shfl_xor(m0, o, 64);
                m1 |= __shfl_xor(m1, o, 64);
                m2 |= __shfl_xor(m2, o, 64);
            }
            if (lane == 0) {
                s_um[0] = m0; s_um[1] = m1; s_um[2] = m2;
                s_winflag = (mycell >= 0 && dupm == 0ull) ? 1 : 0;
            }
        }
        __syncthreads();

        const bool winner = (s_winflag != 0);        // block-uniform

        // Per-thread contribution into 5 category accumulators (≤1 nonzero)
        float a0 = 0.f, a1 = 0.f, a2 = 0.f, a3 = 0.f, a4 = 0.f;
        if (winner && f < 85) {
            if (f == 0) {
                const float d = sigmoidf_(val) - s_geo[t][0];
                a0 = d * d;
            } else if (f == 1) {
                const float d = sigmoidf_(val) - s_geo[t][1];
                a0 = d * d;
            } else if (f == 2) {
                const float e = val - s_geo[t][2];
                a1 = e * e;
            } else if (f == 3) {
                const float e = val - s_geo[t][3];
                a1 = e * e;
            } else if (f == 4) {
                a3 = focal1(val);
                a4 = -focal0(val);       // correction to all-cell neg sum
            } else {
                const int c = f - 5;
                const bool ts = (c < 32) ? ((s_um[0] >> c) & 1)
                              : (c < 64) ? ((s_um[1] >> (c - 32)) & 1)
                                         : ((s_um[2] >> (c - 64)) & 1);
                a2 = ts ? focal1(val) : focal0(val);
            }
        }
        // wave-wide reduce of the 5 accumulators (replaces 85 LDS atomics)
        #pragma unroll
        for (int o = 32; o; o >>= 1) {
            a0 += __shfl_down(a0, o, 64); a1 += __shfl_down(a1, o, 64);
            a2 += __shfl_down(a2, o, 64); a3 += __shfl_down(a3, o, 64);
            a4 += __shfl_down(a4, o, 64);
        }
        if (lane == 0) {
            s_red[wid][0] = a0; s_red[wid][1] = a1; s_red[wid][2] = a2;
            s_red[wid][3] = a3; s_red[wid][4] = a4;
        }
        __syncthreads();
        float* slot = ws + (size_t)bid * 8;          // plain distinct-address
        if (f < 8) {                                 // stores (R8-proven)
            float v = 0.f;
            if (winner) {
                if (f < 5)       v = s_red[0][f] + s_red[1][f];
                else if (f == 5) v = 1.f;
            }
            slot[f] = v;
        }
    } else {
        // ================= all-cell negative path (R8 verbatim) ============
        // float4 counts: scale0 76800 (q 0..599), scale1 19200 (600..749),
        // scale2 4800 (750..787, last block half-active).
        const int q   = bid - OBJ_BLOCKS;
        const int idx = q * 128 + f;
        float sum = 0.f;
        if (idx < 100800) {
            int q4, plane4;
            const float* P;
            if (idx < 76800)      { P = p0; q4 = idx;          plane4 = 1600; }
            else if (idx < 96000) { P = p1; q4 = idx - 76800;  plane4 = 400;  }
            else                  { P = p2; q4 = idx - 96000;  plane4 = 100;  }
            const int plane = q4 / plane4;
            const int r4 = q4 - plane * plane4;
            const int b = plane / 3;
            const int a = plane - b * 3;
            const int HW = plane4 * 4;
            const float4 v = *reinterpret_cast<const float4*>(
                P + (size_t)(b * 255 + a * 85 + 4) * HW + (size_t)r4 * 4);
            sum = focal0(v.x) + focal0(v.y) + focal0(v.z) + focal0(v.w);
        }
        #pragma unroll
        for (int off = 32; off; off >>= 1) sum += __shfl_down(sum, off, 64);
        if ((f & 63) == 0) s_ns[f >> 6] = sum;
        __syncthreads();
        if (f == 0) ws[NEG_BASE + q] = s_ns[0] + s_ns[1];
    }
}

// ---- Kernel F: reduce all partials + finalize scalar (R8 verbatim) ----
__global__ __launch_bounds__(512)
void finalize_kernel(const float* __restrict__ ws,
                     float* __restrict__ out) {
    __shared__ float s_red[8][6];
    __shared__ float s_nred[8][3];
    __shared__ float s_total;
    const int tid  = threadIdx.x;            // 512 threads
    const int lane = tid & 63;
    const int wid  = tid >> 6;
    if (tid == 0) s_total = 0.f;

    // neg partials -> per-scale sums
    float n0 = 0.f, n1 = 0.f, n2 = 0.f;
    for (int q = tid; q < NEG_BLOCKS; q += 512) {
        const float v = ws[NEG_BASE + q];
        if (q < 600)      n0 += v;
        else if (q < 750) n1 += v;
        else              n2 += v;
    }
    #pragma unroll
    for (int off = 32; off; off >>= 1) {
        n0 += __shfl_down(n0, off, 64);
        n1 += __shfl_down(n1, off, 64);
        n2 += __shfl_down(n2, off, 64);
    }
    if (lane == 0) { s_nred[wid][0] = n0; s_nred[wid][1] = n1; s_nred[wid][2] = n2; }

    // obj slots -> per-scale sums + final scalar
    #pragma unroll 1
    for (int s = 0; s < 3; ++s) {
        const float* slot = ws + (size_t)(s * 512 + tid) * 8;
        float v[6];
        #pragma unroll
        for (int k = 0; k < 6; ++k) v[k] = slot[k];
        #pragma unroll
        for (int off = 32; off; off >>= 1)
            #pragma unroll
            for (int k = 0; k < 6; ++k) v[k] += __shfl_down(v[k], off, 64);
        if (lane == 0) {
            #pragma unroll
            for (int k = 0; k < 6; ++k) s_red[wid][k] = v[k];
        }
        __syncthreads();
        if (tid == 0) {
            float sum[6] = {0.f, 0.f, 0.f, 0.f, 0.f, 0.f};
            float negs = 0.f;
            for (int wv = 0; wv < 8; ++wv) {
                #pragma unroll
                for (int k = 0; k < 6; ++k) sum[k] += s_red[wv][k];
                negs += s_nred[wv][s];
            }
            const float Ns = (s == 0) ? (float)(16 * 3 * 6400)
                           : (s == 1) ? (float)(16 * 3 * 1600)
                                      : (float)(16 * 3 * 400);
            const float n_obj   = sum[5];
            const float n_noobj = Ns - n_obj;
            const float lxywh = (sum[0] + sum[1]) / fmaxf(2.f * n_obj, 1.f);
            const float lcls  = sum[2] / fmaxf(n_obj * (float)NUM_CLASSES, 1.f);
            const float lpos  = sum[3] / fmaxf(n_obj, 1.f);
            const float lneg  = (negs + sum[4]) / fmaxf(n_noobj, 1.f);
            const float has   = (n_obj > 0.f) ? 1.f : 0.f;
            s_total += 5.f * lxywh * has + lpos * has + 0.5f * lneg + lcls * has;
        }
        __syncthreads();
    }
    if (tid == 0) out[0] = s_total / 3.f;
}

extern "C" void kernel_launch(void* const* d_in, const int* in_sizes, int n_in,
                              void* d_out, int out_size, void* d_ws, size_t ws_size,
                              hipStream_t stream) {
    const float* p0  = (const float*)d_in[0];
    const float* p1  = (const float*)d_in[1];
    const float* p2  = (const float*)d_in[2];
    const float* tgt = (const float*)d_in[3];
    float* ws  = (float*)d_ws;   // needs (1536*8 + 788) floats ~= 52 KB
    float* out = (float*)d_out;

    work_kernel<<<TOTAL_BLOCKS, 128, 0, stream>>>(p0, p1, p2, tgt, ws);
    finalize_kernel<<<1, 512, 0, stream>>>(ws, out);
}